// Round 16
// baseline (480.766 us; speedup 1.0000x reference)
//
#include <hip/hip_runtime.h>
#include <math.h>

#define NPTS 1024
#define NBATCH 8
#define KNN 20
#define KC 24          // candidate guard band for two-stage kNN
#define EPSBN 1e-5f
#define NSLOPE 0.2f

typedef __attribute__((ext_vector_type(8))) short short8_t;
typedef __attribute__((ext_vector_type(4))) float floatx4;

__device__ __forceinline__ float lrelu_f(float x){ return x >= 0.f ? x : NSLOPE*x; }

__device__ __forceinline__ unsigned short f2bf_rne(float f){
  union { float f; unsigned u; } x; x.f = f;
  unsigned r = x.u + 0x7FFFu + ((x.u >> 16) & 1u);
  return (unsigned short)(r >> 16);
}
__device__ __forceinline__ float bf2f(unsigned short h){
  union { float f; unsigned u; } x; x.u = ((unsigned)h) << 16;
  return x.f;
}
__device__ __forceinline__ unsigned sortkey(float f, int j){
  unsigned u = __float_as_uint(f);
  unsigned msk = (unsigned)(((int)u) >> 31) | 0x80000000u;
  return ((u ^ msk) & 0xFFFFFFF0u) | (unsigned)j;
}

// ---------------- fused prep: X (b,c,n) -> XS hi/lo (b,n,Cp), XT (b,n,C), XX[b,n] ----------------
__global__ __launch_bounds__(256) void prep(const float* __restrict__ X, long bstride, int coff,
                                            int C, int Cp,
                                            unsigned short* __restrict__ Sh,
                                            unsigned short* __restrict__ Sl,
                                            float* __restrict__ XT, float* __restrict__ XX){
  __shared__ float tile[128][33];
  __shared__ float part[32][8];
  int b = blockIdx.y;
  int n0 = blockIdx.x * 32;
  int t = threadIdx.x;
  int r = t >> 3, q = t & 7;
  for (int c0 = 0; c0 < C; c0 += 32){
    int row = c0 + r;
    if (row < C){
      float4 rv = *(const float4*)(X + (size_t)b*bstride + (size_t)(coff+row)*NPTS + n0 + q*4);
      tile[row][q*4+0] = rv.x; tile[row][q*4+1] = rv.y;
      tile[row][q*4+2] = rv.z; tile[row][q*4+3] = rv.w;
    }
  }
  __syncthreads();
  size_t bn = (size_t)b*NPTS + n0 + r;
  for (int c0 = 0; c0 < Cp; c0 += 32){
    int c = c0 + q*4;
    float f0 = (c+0 < C) ? tile[c+0][r] : 0.f;
    float f1 = (c+1 < C) ? tile[c+1][r] : 0.f;
    float f2 = (c+2 < C) ? tile[c+2][r] : 0.f;
    float f3 = (c+3 < C) ? tile[c+3][r] : 0.f;
    if (C >= 32 && c < C)
      *(float4*)(XT + bn*C + c) = make_float4(f0,f1,f2,f3);
    ushort4 oh, ol;
    oh.x = f2bf_rne(f0); ol.x = f2bf_rne(f0 - bf2f(oh.x));
    oh.y = f2bf_rne(f1); ol.y = f2bf_rne(f1 - bf2f(oh.y));
    oh.z = f2bf_rne(f2); ol.z = f2bf_rne(f2 - bf2f(oh.z));
    oh.w = f2bf_rne(f3); ol.w = f2bf_rne(f3 - bf2f(oh.w));
    *(ushort4*)(Sh + bn*Cp + c) = oh;
    *(ushort4*)(Sl + bn*Cp + c) = ol;
  }
  float s = 0.f;
  for (int c = q; c < C; c += 8){ float v = tile[c][r]; s += v*v; }
  part[r][q] = s;
  __syncthreads();
  if (q == 0){
    float s8 = 0.f;
    #pragma unroll
    for (int i = 0; i < 8; ++i) s8 += part[r][i];
    XX[(size_t)b*NPTS + n0 + r] = s8;
  }
}

// ---------------- pd stage-1 via bf16x3 MFMA, 64x64 tile; emits sortable u32 keys ----------------
// key[b,n,m] = sortkey(2*dot(x_n,x_m) - xx[m], m&15)
#define LROW 40
__global__ __launch_bounds__(256) void pd_mfma64(
    const unsigned short* __restrict__ Sh, const unsigned short* __restrict__ Sl,
    int Cp, const float* __restrict__ XX, unsigned* __restrict__ PD){
  __shared__ __align__(16) unsigned short Ah[64*LROW];
  __shared__ __align__(16) unsigned short Al[64*LROW];
  __shared__ __align__(16) unsigned short Bh[64*LROW];
  __shared__ __align__(16) unsigned short Bl[64*LROW];
  int b  = blockIdx.z;
  int n0 = blockIdx.x * 64;
  int m0 = blockIdx.y * 64;
  int t = threadIdx.x;
  int lane = t & 63, wid = t >> 6;
  int wm = (wid & 1) * 32;
  int wn = (wid >> 1) * 32;
  int fr = lane & 15;
  int fq = (lane >> 4) * 8;
  floatx4 acc[2][2];
  #pragma unroll
  for (int i = 0; i < 2; ++i)
    #pragma unroll
    for (int j = 0; j < 2; ++j) acc[i][j] = (floatx4)(0.f);

  int srow = t >> 2, spart = (t & 3)*8;
  for (int k0 = 0; k0 < Cp; k0 += 32){
    size_t ga = ((size_t)b*NPTS + m0 + srow)*Cp + k0 + spart;
    size_t gb = ((size_t)b*NPTS + n0 + srow)*Cp + k0 + spart;
    *(short8_t*)&Ah[srow*LROW + spart] = *(const short8_t*)&Sh[ga];
    *(short8_t*)&Al[srow*LROW + spart] = *(const short8_t*)&Sl[ga];
    *(short8_t*)&Bh[srow*LROW + spart] = *(const short8_t*)&Sh[gb];
    *(short8_t*)&Bl[srow*LROW + spart] = *(const short8_t*)&Sl[gb];
    __syncthreads();
    short8_t afh[2], afl[2], bfh[2], bfl[2];
    #pragma unroll
    for (int mi = 0; mi < 2; ++mi){
      int r = (wm + mi*16 + fr)*LROW + fq;
      afh[mi] = *(const short8_t*)&Ah[r];
      afl[mi] = *(const short8_t*)&Al[r];
    }
    #pragma unroll
    for (int ni = 0; ni < 2; ++ni){
      int r = (wn + ni*16 + fr)*LROW + fq;
      bfh[ni] = *(const short8_t*)&Bh[r];
      bfl[ni] = *(const short8_t*)&Bl[r];
    }
    #pragma unroll
    for (int mi = 0; mi < 2; ++mi)
      #pragma unroll
      for (int ni = 0; ni < 2; ++ni){
        acc[mi][ni] = __builtin_amdgcn_mfma_f32_16x16x32_bf16(afh[mi], bfh[ni], acc[mi][ni], 0, 0, 0);
        acc[mi][ni] = __builtin_amdgcn_mfma_f32_16x16x32_bf16(afl[mi], bfh[ni], acc[mi][ni], 0, 0, 0);
        acc[mi][ni] = __builtin_amdgcn_mfma_f32_16x16x32_bf16(afh[mi], bfl[ni], acc[mi][ni], 0, 0, 0);
      }
    __syncthreads();
  }
  int col = lane & 15;
  int rquad = (lane >> 4) * 4;
  #pragma unroll
  for (int mi = 0; mi < 2; ++mi)
    #pragma unroll
    for (int ni = 0; ni < 2; ++ni){
      int n = n0 + wn + ni*16 + col;
      int mbase = m0 + wm + mi*16 + rquad;   // mbase & 15 == rquad (all terms mult of 16)
      float4 xx4 = *(const float4*)(XX + (size_t)b*NPTS + mbase);
      floatx4 a = acc[mi][ni];
      uint4 o;
      o.x = sortkey(2.f*a.x - xx4.x, rquad+0);
      o.y = sortkey(2.f*a.y - xx4.y, rquad+1);
      o.z = sortkey(2.f*a.z - xx4.z, rquad+2);
      o.w = sortkey(2.f*a.w - xx4.w, rquad+3);
      *(uint4*)(PD + ((size_t)b*NPTS + n)*NPTS + mbase) = o;
    }
}

// ---------------- fused top-24 + f64 refine (keys pre-built; rank via LDS broadcast) ----------------
__global__ __launch_bounds__(256) void topk_refine(const unsigned* __restrict__ PD,
                                                   const float* __restrict__ X, long bstride,
                                                   int coff, int C,
                                                   const float* __restrict__ XT,
                                                   int* __restrict__ IDX){
  __shared__ double sp[4][32];
  __shared__ int    si[4][32];
  int wid = threadIdx.x >> 6;
  int lane = threadIdx.x & 63;
  int row = blockIdx.x*4 + wid;       // b*NPTS + n
  int b = row >> 10, n = row & 1023;
  const unsigned* p = PD + (size_t)row*NPTS;
  unsigned key[16];
  #pragma unroll
  for (int j4 = 0; j4 < 4; ++j4){
    uint4 t4 = *(const uint4*)&p[lane*16 + j4*4];
    key[j4*4+0] = t4.x; key[j4*4+1] = t4.y; key[j4*4+2] = t4.z; key[j4*4+3] = t4.w;
  }
  // bitonic sort 16 keys descending
  #pragma unroll
  for (int ksz = 2; ksz <= 16; ksz <<= 1){
    #pragma unroll
    for (int jj = ksz >> 1; jj > 0; jj >>= 1){
      #pragma unroll
      for (int i = 0; i < 16; ++i){
        int l = i ^ jj;
        if (l > i){
          unsigned a = key[i], c = key[l];
          unsigned mx = a > c ? a : c, mn = a > c ? c : a;
          bool maxfirst = ((i & ksz) == 0);
          key[i] = maxfirst ? mx : mn;
          key[l] = maxfirst ? mn : mx;
        }
      }
    }
  }
  int my_m = 0;
  #pragma unroll
  for (int k = 0; k < KC; ++k){
    unsigned h = key[0];
    unsigned g = h, o;
    o = (unsigned)__builtin_amdgcn_update_dpp(0, (int)g, 0x121, 0xF, 0xF, true);
    g = o > g ? o : g;
    o = (unsigned)__builtin_amdgcn_update_dpp(0, (int)g, 0x122, 0xF, 0xF, true);
    g = o > g ? o : g;
    o = (unsigned)__builtin_amdgcn_update_dpp(0, (int)g, 0x124, 0xF, 0xF, true);
    g = o > g ? o : g;
    o = (unsigned)__builtin_amdgcn_update_dpp(0, (int)g, 0x128, 0xF, 0xF, true);
    g = o > g ? o : g;
    o = (unsigned)__builtin_amdgcn_ds_swizzle((int)g, 0x401F);
    g = o > g ? o : g;
    o = (unsigned)__shfl_xor((int)g, 32, 64);
    g = o > g ? o : g;
    unsigned long long ball = __ballot(h == g);
    int wl = __ffsll(ball) - 1;
    if ((lane & 31) == k) my_m = wl*16 + (int)(g & 15u);   // lanes k AND k+32 record
    bool isw = (lane == wl);
    #pragma unroll
    for (int i2 = 0; i2 < 15; ++i2) key[i2] = isw ? key[i2+1] : key[i2];
    key[15] = isw ? 0u : key[15];
  }
  // exact f64 refine, split: lane k sums c in [0,C/2), lane k+32 sums [C/2,C)
  int lk = lane & 31;
  double pdv = -1e300; int midx = (1 << 20) + lane;
  if (lk < KC){
    midx = my_m;
    double dot = 0.0, m2 = 0.0, n2 = 0.0;
    if (C == 3){
      if (lane < 32){
        const float* Xb = X + (size_t)b*bstride + (size_t)coff*NPTS;
        #pragma unroll
        for (int c = 0; c < 3; ++c){
          double xn = (double)Xb[(size_t)c*NPTS + n];
          double xm = (double)Xb[(size_t)c*NPTS + my_m];
          dot += xn*xm; m2 += xm*xm; n2 += xn*xn;
        }
      }
    } else {
      int C2 = C >> 1;
      int cbeg = (lane < 32) ? 0 : C2;
      int cend = (lane < 32) ? C2 : C;
      const float* rn = XT + ((size_t)b*NPTS + n)*C;
      const float* rm = XT + ((size_t)b*NPTS + my_m)*C;
      for (int c = cbeg; c < cend; c += 4){
        float4 xn4 = *(const float4*)&rn[c];
        float4 xm4 = *(const float4*)&rm[c];
        dot += (double)xn4.x*(double)xm4.x + (double)xn4.y*(double)xm4.y
             + (double)xn4.z*(double)xm4.z + (double)xn4.w*(double)xm4.w;
        m2  += (double)xm4.x*(double)xm4.x + (double)xm4.y*(double)xm4.y
             + (double)xm4.z*(double)xm4.z + (double)xm4.w*(double)xm4.w;
        n2  += (double)xn4.x*(double)xn4.x + (double)xn4.y*(double)xn4.y
             + (double)xn4.z*(double)xn4.z + (double)xn4.w*(double)xn4.w;
      }
    }
    // combine the two half-sums (pairs (k, k+32) both active)
    double od = __shfl_xor(dot, 32, 64);
    double om = __shfl_xor(m2, 32, 64);
    double on = __shfl_xor(n2, 32, 64);
    dot += od; m2 += om; n2 += on;
    pdv = (2.0*dot - m2) - n2;
  }
  // rank via same-wave LDS broadcast (avoids 72 bpermutes)
  if (lane < KC){ sp[wid][lane] = pdv; si[wid][lane] = midx; }
  int rank = 0;
  #pragma unroll
  for (int j = 0; j < KC; ++j){
    double ov = sp[wid][j];
    int    oi = si[wid][j];
    rank += (ov > pdv || (ov == pdv && oi < midx)) ? 1 : 0;
  }
  if (lane < KC && rank < KNN) IDX[(size_t)row*KNN + rank] = midx;
}

// ---------------- OUT[b,m,n] = sum_c A[m,c]*X[b,c,n]; A rows: [0,O)=w1, [O,2O)=w2-w1 ----------------
__global__ __launch_bounds__(256) void lin_gemm64(const float* __restrict__ W, int M, int Cdim,
                                                  int lda, int O,
                                                  const float* __restrict__ X, long bstride,
                                                  int coff, float* __restrict__ OUT){
  __shared__ float As[16][68];   // As[k][m]
  __shared__ float Bs[16][68];   // Bs[k][n]
  int b = blockIdx.z;
  int m0 = blockIdx.y * 64;
  int n0 = blockIdx.x * 64;
  int t = threadIdx.x;
  const float* Xb = X + (size_t)b*bstride + (size_t)coff*NPTS;
  float acc[4][4] = {};
  int lr = t >> 4, lc = (t & 15) << 2;
  int tr = (t >> 4) << 2, tc = (t & 15) << 2;
  for (int k0 = 0; k0 < Cdim; k0 += 16){
    int c = k0 + lr;
    float4 av = make_float4(0,0,0,0);
    if (c < Cdim){
      #pragma unroll
      for (int j = 0; j < 4; ++j){
        int m = m0 + lc + j;
        float aval = (m < O) ? W[(size_t)m*lda + c]
                             : W[(size_t)(m-O)*lda + Cdim + c] - W[(size_t)(m-O)*lda + c];
        ((float*)&av)[j] = aval;
      }
    }
    float4 bv = make_float4(0,0,0,0);
    if (c < Cdim)
      bv = *(const float4*)(Xb + (size_t)c*NPTS + n0 + lc);
    *(float4*)&As[lr][lc] = av;
    *(float4*)&Bs[lr][lc] = bv;
    __syncthreads();
    #pragma unroll
    for (int kk = 0; kk < 16; ++kk){
      float4 a4 = *(const float4*)&As[kk][tr];
      float4 b4 = *(const float4*)&Bs[kk][tc];
      float a[4] = {a4.x,a4.y,a4.z,a4.w};
      float bb[4] = {b4.x,b4.y,b4.z,b4.w};
      #pragma unroll
      for (int i = 0; i < 4; ++i)
        #pragma unroll
        for (int j = 0; j < 4; ++j) acc[i][j] += a[i]*bb[j];
    }
    __syncthreads();
  }
  #pragma unroll
  for (int i = 0; i < 4; ++i){
    int m = m0 + tr + i;
    *(float4*)(OUT + ((size_t)b*M + m)*NPTS + n0 + tc) =
        make_float4(acc[i][0],acc[i][1],acc[i][2],acc[i][3]);
  }
}

// ---------------- per (b,o): ymax/ymin over k of (u[n] + v[idx[n,k]]) + BN partial sums --------
__global__ void edge_stats(const float* __restrict__ V, const int* __restrict__ IDX, int O,
                           float* __restrict__ YMX, float* __restrict__ YMN,
                           float* __restrict__ S1P, float* __restrict__ S2P){
  __shared__ float vrow[NPTS];
  __shared__ float urow[NPTS];
  __shared__ float r1[256];
  __shared__ float r2[256];
  int b = blockIdx.x / O;
  int o = blockIdx.x % O;
  int t = threadIdx.x;
  const float* vp = V + ((size_t)b*2*O + o)*NPTS;
  const float* up = V + ((size_t)b*2*O + O + o)*NPTS;
  for (int i = 0; i < 4; ++i){ vrow[t+256*i] = vp[t+256*i]; urow[t+256*i] = up[t+256*i]; }
  __syncthreads();
  float s1 = 0.f, s2 = 0.f;
  size_t obase = ((size_t)b*O + o)*NPTS;
  for (int i = 0; i < 4; ++i){
    int n = t + 256*i;
    float un = urow[n];
    const int* ip = IDX + ((size_t)b*NPTS + n)*KNN;
    float mx = -1e38f, mn = 1e38f;
    #pragma unroll
    for (int k = 0; k < KNN; ++k){
      float val = un + vrow[ip[k]];
      mx = fmaxf(mx, val); mn = fminf(mn, val);
      s1 += val; s2 += val*val;
    }
    YMX[obase + n] = mx;
    YMN[obase + n] = mn;
  }
  r1[t] = s1; r2[t] = s2;
  __syncthreads();
  for (int s = 128; s > 0; s >>= 1){
    if (t < s){ r1[t] += r1[t+s]; r2[t] += r2[t+s]; }
    __syncthreads();
  }
  if (t == 0){ S1P[b*O + o] = r1[0]; S2P[b*O + o] = r2[0]; }
}

// ---------------- apply BN(inline finalize)+lrelu to max-over-k, write into CAT slice ----------------
__global__ void edge_apply(const float* __restrict__ YMX, const float* __restrict__ YMN,
                           const float* __restrict__ S1P, const float* __restrict__ S2P,
                           const float* __restrict__ gw, const float* __restrict__ gb,
                           int O, float* __restrict__ CAT, int coff_out){
  int g = blockIdx.x*blockDim.x + threadIdx.x;
  int n = g & (NPTS-1);
  int o = (g >> 10) % O;
  int b = (g >> 10) / O;
  float s1 = 0.f, s2 = 0.f;
  #pragma unroll
  for (int i = 0; i < NBATCH; ++i){ s1 += S1P[i*O + o]; s2 += S2P[i*O + o]; }
  const float cnt = (float)(NBATCH*NPTS*KNN);
  float mean = s1 / cnt;
  float var = fmaxf(s2 / cnt - mean*mean, 0.f);
  float sc = gw[o] * rsqrtf(var + EPSBN);
  float sh = gb[o] - mean*sc;
  float v = (sc >= 0.f) ? YMX[g] : YMN[g];
  CAT[((size_t)b*512 + coff_out + o)*NPTS + n] = lrelu_f(sc*v + sh);
}

// ---------------- W -> bf16 hi/lo split ----------------
__global__ void wsplit(const float* __restrict__ W, int nelem,
                       unsigned short* __restrict__ Wh, unsigned short* __restrict__ Wl){
  int i = blockIdx.x*blockDim.x + threadIdx.x;
  if (i >= nelem) return;
  float f = W[i];
  unsigned short hi = f2bf_rne(f);
  Wh[i] = hi;
  Wl[i] = f2bf_rne(f - bf2f(hi));
}

// ---------------- CAT (b,c,n) -> CATt (b,n,c) bf16 hi/lo, LDS tile transpose ----------------
__global__ void catsplit_t(const float* __restrict__ CAT,
                           unsigned short* __restrict__ Th, unsigned short* __restrict__ Tl){
  __shared__ float tile[32][33];
  int b = blockIdx.z;
  int c0 = blockIdx.y * 32;
  int n0 = blockIdx.x * 32;
  int t = threadIdx.x;
  int r = t >> 3, q = t & 7;
  float4 rv = *(const float4*)(CAT + ((size_t)b*512 + c0 + r)*NPTS + n0 + q*4);
  tile[r][q*4+0] = rv.x; tile[r][q*4+1] = rv.y; tile[r][q*4+2] = rv.z; tile[r][q*4+3] = rv.w;
  __syncthreads();
  ushort4 oh, ol;
  float f0 = tile[q*4+0][r], f1 = tile[q*4+1][r], f2 = tile[q*4+2][r], f3 = tile[q*4+3][r];
  oh.x = f2bf_rne(f0); ol.x = f2bf_rne(f0 - bf2f(oh.x));
  oh.y = f2bf_rne(f1); ol.y = f2bf_rne(f1 - bf2f(oh.y));
  oh.z = f2bf_rne(f2); ol.z = f2bf_rne(f2 - bf2f(oh.z));
  oh.w = f2bf_rne(f3); ol.w = f2bf_rne(f3 - bf2f(oh.w));
  size_t ob = ((size_t)b*NPTS + n0 + r)*512 + c0 + q*4;
  *(ushort4*)(Th + ob) = oh;
  *(ushort4*)(Tl + ob) = ol;
}

// ---------------- conv5 via bf16x3 MFMA, 128n x 64m tile (1024 blocks, 4/CU) ----------------
// Y5[b,m,n] = sum_c W[m,c]*CAT[b,c,n]. A = CATt n-rows (128), B = W m-rows (64); D row=n, col=m.
__global__ __launch_bounds__(256) void conv5_mfma(
    const unsigned short* __restrict__ Ath, const unsigned short* __restrict__ Atl,
    const unsigned short* __restrict__ Wh,  const unsigned short* __restrict__ Wl,
    float* __restrict__ OUT){
  __shared__ __align__(16) unsigned short Ah[128*LROW];
  __shared__ __align__(16) unsigned short Al[128*LROW];
  __shared__ __align__(16) unsigned short Bh[64*LROW];
  __shared__ __align__(16) unsigned short Bl[64*LROW];
  int b  = blockIdx.z;
  int n0 = blockIdx.x * 128;
  int m0 = blockIdx.y * 64;
  int t = threadIdx.x;
  int lane = t & 63, wid = t >> 6;
  int wn = (wid & 1) * 64;
  int wm = (wid >> 1) * 32;
  int fr = lane & 15;
  int fq = (lane >> 4) * 8;
  floatx4 acc[4][2];
  #pragma unroll
  for (int i = 0; i < 4; ++i)
    #pragma unroll
    for (int j = 0; j < 2; ++j) acc[i][j] = (floatx4)(0.f);

  int srowB = t >> 2, spartB = (t & 3)*8;
  for (int k0 = 0; k0 < 512; k0 += 32){
    #pragma unroll
    for (int c = 0; c < 2; ++c){
      int ch = t + 256*c;
      int row = ch >> 2, part = (ch & 3)*8;
      size_t ga = ((size_t)b*NPTS + n0 + row)*512 + k0 + part;
      *(short8_t*)&Ah[row*LROW + part] = *(const short8_t*)&Ath[ga];
      *(short8_t*)&Al[row*LROW + part] = *(const short8_t*)&Atl[ga];
    }
    {
      size_t gb = ((size_t)(m0 + srowB))*512 + k0 + spartB;
      *(short8_t*)&Bh[srowB*LROW + spartB] = *(const short8_t*)&Wh[gb];
      *(short8_t*)&Bl[srowB*LROW + spartB] = *(const short8_t*)&Wl[gb];
    }
    __syncthreads();
    short8_t afh[4], afl[4], bfh[2], bfl[2];
    #pragma unroll
    for (int ni = 0; ni < 4; ++ni){
      int r = (wn + ni*16 + fr)*LROW + fq;
      afh[ni] = *(const short8_t*)&Ah[r];
      afl[ni] = *(const short8_t*)&Al[r];
    }
    #pragma unroll
    for (int mi = 0; mi < 2; ++mi){
      int r = (wm + mi*16 + fr)*LROW + fq;
      bfh[mi] = *(const short8_t*)&Bh[r];
      bfl[mi] = *(const short8_t*)&Bl[r];
    }
    #pragma unroll
    for (int ni = 0; ni < 4; ++ni)
      #pragma unroll
      for (int mi = 0; mi < 2; ++mi){
        acc[ni][mi] = __builtin_amdgcn_mfma_f32_16x16x32_bf16(afh[ni], bfh[mi], acc[ni][mi], 0, 0, 0);
        acc[ni][mi] = __builtin_amdgcn_mfma_f32_16x16x32_bf16(afl[ni], bfh[mi], acc[ni][mi], 0, 0, 0);
        acc[ni][mi] = __builtin_amdgcn_mfma_f32_16x16x32_bf16(afh[ni], bfl[mi], acc[ni][mi], 0, 0, 0);
      }
    __syncthreads();
  }
  int col = lane & 15;
  int rquad = (lane >> 4) * 4;
  #pragma unroll
  for (int ni = 0; ni < 4; ++ni)
    #pragma unroll
    for (int mi = 0; mi < 2; ++mi){
      int m = m0 + wm + mi*16 + col;
      int n = n0 + wn + ni*16 + rquad;
      *(floatx4*)(OUT + ((size_t)b*1024 + m)*NPTS + n) = acc[ni][mi];
    }
}

// ---------------- conv5 BN stats ----------------
__global__ void y5_stats(const float* __restrict__ Y5, float* __restrict__ S1, float* __restrict__ S2){
  __shared__ float r1[256], r2[256];
  int o = blockIdx.x;
  int t = threadIdx.x;
  float s1 = 0.f, s2 = 0.f;
  for (int b = 0; b < NBATCH; ++b){
    const float* p = Y5 + ((size_t)b*1024 + o)*NPTS;
    for (int n = t; n < NPTS; n += 256){ float v = p[n]; s1 += v; s2 += v*v; }
  }
  r1[t] = s1; r2[t] = s2;
  __syncthreads();
  for (int s = 128; s > 0; s >>= 1){
    if (t < s){ r1[t] += r1[t+s]; r2[t] += r2[t+s]; }
    __syncthreads();
  }
  if (t == 0){ S1[o] = r1[0]; S2[o] = r2[0]; }
}

// ---------------- head: feat = [max_n, mean_n] of lrelu(BN(y5)), inline finalize ----------------
__global__ void head_kernel(const float* __restrict__ Y5, const float* __restrict__ S1,
                            const float* __restrict__ S2,
                            const float* __restrict__ gw, const float* __restrict__ gb,
                            float* __restrict__ FEAT){
  __shared__ float rm[256], rs[256];
  int o = blockIdx.x & 1023;
  int b = blockIdx.x >> 10;
  int t = threadIdx.x;
  const float cnt = (float)(NBATCH*NPTS);
  float mean = S1[o] / cnt;
  float var = fmaxf(S2[o] / cnt - mean*mean, 0.f);
  float s = gw[o] * rsqrtf(var + EPSBN);
  float sh = gb[o] - mean*s;
  const float* p = Y5 + ((size_t)b*1024 + o)*NPTS;
  float mx = -1e38f, sm = 0.f;
  for (int n = t; n < NPTS; n += 256){
    float v = lrelu_f(s*p[n] + sh);
    mx = fmaxf(mx, v); sm += v;
  }
  rm[t] = mx; rs[t] = sm;
  __syncthreads();
  for (int st = 128; st > 0; st >>= 1){
    if (t < st){ rm[t] = fmaxf(rm[t], rm[t+st]); rs[t] += rs[t+st]; }
    __syncthreads();
  }
  if (t == 0){
    FEAT[(size_t)b*2048 + o]        = rm[0];
    FEAT[(size_t)b*2048 + 1024 + o] = rs[0] * (1.f/NPTS);
  }
}

// ---------------- FC + batch-BN(8) + lrelu ----------------
__global__ void fc_bn(const float* __restrict__ IN, int ID, int OD,
                      const float* __restrict__ W, const float* __restrict__ bias,
                      const float* __restrict__ gw, const float* __restrict__ gb,
                      float* __restrict__ OUT){
  __shared__ float red[256][8];
  int f = blockIdx.x;
  int t = threadIdx.x;
  float acc[8] = {};
  const float* wr = W + (size_t)f*ID;
  for (int j = t; j < ID; j += 256){
    float wv = wr[j];
    #pragma unroll
    for (int b = 0; b < 8; ++b) acc[b] += IN[b*ID + j] * wv;
  }
  #pragma unroll
  for (int b = 0; b < 8; ++b) red[t][b] = acc[b];
  __syncthreads();
  for (int s = 128; s > 0; s >>= 1){
    if (t < s){
      #pragma unroll
      for (int b = 0; b < 8; ++b) red[t][b] += red[t+s][b];
    }
    __syncthreads();
  }
  if (t == 0){
    float h[8], mean = 0.f;
    #pragma unroll
    for (int b = 0; b < 8; ++b){ h[b] = red[0][b] + bias[f]; mean += h[b]; }
    mean *= 0.125f;
    float var = 0.f;
    #pragma unroll
    for (int b = 0; b < 8; ++b){ float d = h[b]-mean; var += d*d; }
    var *= 0.125f;
    float sc = gw[f]*rsqrtf(var + EPSBN);
    float sh = gb[f] - mean*sc;
    #pragma unroll
    for (int b = 0; b < 8; ++b) OUT[b*OD + f] = lrelu_f(sc*h[b] + sh);
  }
}

// ---------------- final linear (no BN) ----------------
__global__ void fc_out(const float* __restrict__ IN, const float* __restrict__ W,
                       const float* __restrict__ bias, float* __restrict__ OUT){
  __shared__ float red[256][8];
  int j = blockIdx.x;
  int t = threadIdx.x;
  float wv = W[(size_t)j*256 + t];
  #pragma unroll
  for (int b = 0; b < 8; ++b) red[t][b] = IN[b*256 + t] * wv;
  __syncthreads();
  for (int s = 128; s > 0; s >>= 1){
    if (t < s){
      #pragma unroll
      for (int b = 0; b < 8; ++b) red[t][b] += red[t+s][b];
    }
    __syncthreads();
  }
  if (t == 0){
    #pragma unroll
    for (int b = 0; b < 8; ++b) OUT[b*40 + j] = red[0][b] + bias[j];
  }
}

extern "C" void kernel_launch(void* const* d_in, const int* in_sizes, int n_in,
                              void* d_out, int out_size, void* d_ws, size_t ws_size,
                              hipStream_t stream) {
  const float* x   = (const float*)d_in[0];
  const float* cw[5] = { (const float*)d_in[1], (const float*)d_in[2], (const float*)d_in[3],
                         (const float*)d_in[4], (const float*)d_in[5] };
  const float* bw[7]; const float* bbv[7];
  for (int i = 0; i < 7; ++i){ bw[i] = (const float*)d_in[6+2*i]; bbv[i] = (const float*)d_in[7+2*i]; }
  const float* l1w = (const float*)d_in[20]; const float* l1b = (const float*)d_in[21];
  const float* l2w = (const float*)d_in[22]; const float* l2b = (const float*)d_in[23];
  const float* l3w = (const float*)d_in[24]; const float* l3b = (const float*)d_in[25];
  float* out = (float*)d_out;

  float* ws = (float*)d_ws;
  unsigned* PD = (unsigned*)ws;            // u32 sortable keys (edge phase)
  float* V     = ws;
  float* YMX   = ws + 4194304;
  float* YMN   = ws + 6291456;
  float* Y5    = ws;
  float* XT    = ws + 8388608;
  unsigned short* XSH = (unsigned short*)(ws + 9437184);
  unsigned short* XSL = (unsigned short*)(ws + 9961472);
  float* XX    = ws + 10485760;
  unsigned short* CATth = (unsigned short*)(ws + 8388608);
  unsigned short* CATtl = (unsigned short*)(ws + 10485760);
  unsigned short* WhP   = (unsigned short*)(ws + 12582912);
  unsigned short* WlP   = (unsigned short*)(ws + 12845056);
  float* CAT   = ws + 16777216;
  int*   IDX   = (int*)(ws + 20987904);
  float* S1P   = ws + 21151744;
  float* S2P   = ws + 21159936;
  float* FEAT  = ws + 21170176;
  float* H1    = ws + 21186560;
  float* H2    = ws + 21190656;

  struct L { int C, Cp, O; const float* in; long bs; int ci; const float* w; int bn; int co; };
  L ls[4] = {
    { 3,   32,  64, x,   (long)3*NPTS,   0,   cw[0], 0, 0   },
    { 64,  64,  64, CAT, (long)512*NPTS, 0,   cw[1], 1, 64  },
    { 64,  64, 128, CAT, (long)512*NPTS, 64,  cw[2], 2, 128 },
    { 128, 128,256, CAT, (long)512*NPTS, 128, cw[3], 3, 256 },
  };

  for (int li = 0; li < 4; ++li){
    L& l = ls[li];
    prep<<<dim3(32, NBATCH), 256, 0, stream>>>(l.in, l.bs, l.ci, l.C, l.Cp, XSH, XSL, XT, XX);
    pd_mfma64<<<dim3(16,16,NBATCH), 256, 0, stream>>>(XSH, XSL, l.Cp, XX, PD);
    topk_refine<<<(NBATCH*NPTS)/4, 256, 0, stream>>>(PD, l.in, l.bs, l.ci, l.C, XT, IDX);
    lin_gemm64<<<dim3(16, (2*l.O)/64, NBATCH), 256, 0, stream>>>(
        l.w, 2*l.O, l.C, 2*l.C, l.O, l.in, l.bs, l.ci, V);
    edge_stats<<<NBATCH*l.O, 256, 0, stream>>>(V, IDX, l.O, YMX, YMN, S1P, S2P);
    edge_apply<<<(NBATCH*l.O*NPTS)/256, 256, 0, stream>>>(
        YMX, YMN, S1P, S2P, bw[l.bn], bbv[l.bn], l.O, CAT, l.co);
  }

  // conv5 via bf16x3 MFMA (128n x 64m tiles, 1024 blocks)
  wsplit<<<(1024*512+255)/256, 256, 0, stream>>>(cw[4], 1024*512, WhP, WlP);
  catsplit_t<<<dim3(32,16,NBATCH), 256, 0, stream>>>(CAT, CATth, CATtl);
  conv5_mfma<<<dim3(8,16,NBATCH), 256, 0, stream>>>(CATth, CATtl, WhP, WlP, Y5);

  y5_stats<<<1024, 256, 0, stream>>>(Y5, S1P, S2P);
  head_kernel<<<NBATCH*1024, 256, 0, stream>>>(Y5, S1P, S2P, bw[4], bbv[4], FEAT);

  fc_bn<<<512, 256, 0, stream>>>(FEAT, 2048, 512, l1w, l1b, bw[5], bbv[5], H1);
  fc_bn<<<256, 256, 0, stream>>>(H1, 512, 256, l2w, l2b, bw[6], bbv[6], H2);
  fc_out<<<40, 256, 0, stream>>>(H2, l3w, l3b, out);
}

// Round 17
// 474.968 us; speedup vs baseline: 1.0122x; 1.0122x over previous
//
#include <hip/hip_runtime.h>
#include <math.h>

#define NPTS 1024
#define NBATCH 8
#define KNN 20
#define KC 24          // candidate guard band for two-stage kNN
#define EPSBN 1e-5f
#define NSLOPE 0.2f

typedef __attribute__((ext_vector_type(8))) short short8_t;
typedef __attribute__((ext_vector_type(4))) float floatx4;

__device__ __forceinline__ float lrelu_f(float x){ return x >= 0.f ? x : NSLOPE*x; }

__device__ __forceinline__ unsigned short f2bf_rne(float f){
  union { float f; unsigned u; } x; x.f = f;
  unsigned r = x.u + 0x7FFFu + ((x.u >> 16) & 1u);
  return (unsigned short)(r >> 16);
}
__device__ __forceinline__ float bf2f(unsigned short h){
  union { float f; unsigned u; } x; x.u = ((unsigned)h) << 16;
  return x.f;
}
__device__ __forceinline__ unsigned sortkey(float f, int j){
  unsigned u = __float_as_uint(f);
  unsigned msk = (unsigned)(((int)u) >> 31) | 0x80000000u;
  return ((u ^ msk) & 0xFFFFFFF0u) | (unsigned)j;
}

// ---------------- fused prep: X (b,c,n) -> XS hi/lo (b,n,Cp), XT (b,n,C), XX[b,n] ----------------
__global__ __launch_bounds__(256) void prep(const float* __restrict__ X, long bstride, int coff,
                                            int C, int Cp,
                                            unsigned short* __restrict__ Sh,
                                            unsigned short* __restrict__ Sl,
                                            float* __restrict__ XT, float* __restrict__ XX){
  __shared__ float tile[128][33];
  __shared__ float part[32][8];
  int b = blockIdx.y;
  int n0 = blockIdx.x * 32;
  int t = threadIdx.x;
  int r = t >> 3, q = t & 7;
  for (int c0 = 0; c0 < C; c0 += 32){
    int row = c0 + r;
    if (row < C){
      float4 rv = *(const float4*)(X + (size_t)b*bstride + (size_t)(coff+row)*NPTS + n0 + q*4);
      tile[row][q*4+0] = rv.x; tile[row][q*4+1] = rv.y;
      tile[row][q*4+2] = rv.z; tile[row][q*4+3] = rv.w;
    }
  }
  __syncthreads();
  size_t bn = (size_t)b*NPTS + n0 + r;
  for (int c0 = 0; c0 < Cp; c0 += 32){
    int c = c0 + q*4;
    float f0 = (c+0 < C) ? tile[c+0][r] : 0.f;
    float f1 = (c+1 < C) ? tile[c+1][r] : 0.f;
    float f2 = (c+2 < C) ? tile[c+2][r] : 0.f;
    float f3 = (c+3 < C) ? tile[c+3][r] : 0.f;
    if (C >= 32 && c < C)
      *(float4*)(XT + bn*C + c) = make_float4(f0,f1,f2,f3);
    ushort4 oh, ol;
    oh.x = f2bf_rne(f0); ol.x = f2bf_rne(f0 - bf2f(oh.x));
    oh.y = f2bf_rne(f1); ol.y = f2bf_rne(f1 - bf2f(oh.y));
    oh.z = f2bf_rne(f2); ol.z = f2bf_rne(f2 - bf2f(oh.z));
    oh.w = f2bf_rne(f3); ol.w = f2bf_rne(f3 - bf2f(oh.w));
    *(ushort4*)(Sh + bn*Cp + c) = oh;
    *(ushort4*)(Sl + bn*Cp + c) = ol;
  }
  float s = 0.f;
  for (int c = q; c < C; c += 8){ float v = tile[c][r]; s += v*v; }
  part[r][q] = s;
  __syncthreads();
  if (q == 0){
    float s8 = 0.f;
    #pragma unroll
    for (int i = 0; i < 8; ++i) s8 += part[r][i];
    XX[(size_t)b*NPTS + n0 + r] = s8;
  }
}

// ---------------- FUSED: pd stage-1 (MFMA, y<16) + edge lin GEMM (y>=16) ----------------
// pd: key[b,n,m] = sortkey(2*dot-xx[m], m&15), 64x64 tiles.
// lin: V[b,m,n] = sum_c A[m,c]*X[b,c,n]; A rows [0,O)=w1, [O,2O)=w2-w1.
#define LROW 40
__global__ __launch_bounds__(256) void pd_lin(
    const unsigned short* __restrict__ Sh, const unsigned short* __restrict__ Sl,
    int Cp, const float* __restrict__ XX, unsigned* __restrict__ PD,
    const float* __restrict__ W, int M, int Cdim, int lda, int O,
    const float* __restrict__ X, long bstride, int coff, float* __restrict__ V){
  __shared__ __align__(16) char smem[20480];
  int b = blockIdx.z;
  int t = threadIdx.x;
  if (blockIdx.y < 16){
    // ---- pd path (body identical to measured pd_mfma64) ----
    unsigned short* Ah = (unsigned short*)smem;
    unsigned short* Al = Ah + 64*LROW;
    unsigned short* Bh = Al + 64*LROW;
    unsigned short* Bl = Bh + 64*LROW;
    int n0 = blockIdx.x * 64;
    int m0 = blockIdx.y * 64;
    int lane = t & 63, wid = t >> 6;
    int wm = (wid & 1) * 32;
    int wn = (wid >> 1) * 32;
    int fr = lane & 15;
    int fq = (lane >> 4) * 8;
    floatx4 acc[2][2];
    #pragma unroll
    for (int i = 0; i < 2; ++i)
      #pragma unroll
      for (int j = 0; j < 2; ++j) acc[i][j] = (floatx4)(0.f);
    int srow = t >> 2, spart = (t & 3)*8;
    for (int k0 = 0; k0 < Cp; k0 += 32){
      size_t ga = ((size_t)b*NPTS + m0 + srow)*Cp + k0 + spart;
      size_t gb = ((size_t)b*NPTS + n0 + srow)*Cp + k0 + spart;
      *(short8_t*)&Ah[srow*LROW + spart] = *(const short8_t*)&Sh[ga];
      *(short8_t*)&Al[srow*LROW + spart] = *(const short8_t*)&Sl[ga];
      *(short8_t*)&Bh[srow*LROW + spart] = *(const short8_t*)&Sh[gb];
      *(short8_t*)&Bl[srow*LROW + spart] = *(const short8_t*)&Sl[gb];
      __syncthreads();
      short8_t afh[2], afl[2], bfh[2], bfl[2];
      #pragma unroll
      for (int mi = 0; mi < 2; ++mi){
        int r = (wm + mi*16 + fr)*LROW + fq;
        afh[mi] = *(const short8_t*)&Ah[r];
        afl[mi] = *(const short8_t*)&Al[r];
      }
      #pragma unroll
      for (int ni = 0; ni < 2; ++ni){
        int r = (wn + ni*16 + fr)*LROW + fq;
        bfh[ni] = *(const short8_t*)&Bh[r];
        bfl[ni] = *(const short8_t*)&Bl[r];
      }
      #pragma unroll
      for (int mi = 0; mi < 2; ++mi)
        #pragma unroll
        for (int ni = 0; ni < 2; ++ni){
          acc[mi][ni] = __builtin_amdgcn_mfma_f32_16x16x32_bf16(afh[mi], bfh[ni], acc[mi][ni], 0, 0, 0);
          acc[mi][ni] = __builtin_amdgcn_mfma_f32_16x16x32_bf16(afl[mi], bfh[ni], acc[mi][ni], 0, 0, 0);
          acc[mi][ni] = __builtin_amdgcn_mfma_f32_16x16x32_bf16(afh[mi], bfl[ni], acc[mi][ni], 0, 0, 0);
        }
      __syncthreads();
    }
    int col = lane & 15;
    int rquad = (lane >> 4) * 4;
    #pragma unroll
    for (int mi = 0; mi < 2; ++mi)
      #pragma unroll
      for (int ni = 0; ni < 2; ++ni){
        int n = n0 + wn + ni*16 + col;
        int mbase = m0 + wm + mi*16 + rquad;   // mbase & 15 == rquad
        float4 xx4 = *(const float4*)(XX + (size_t)b*NPTS + mbase);
        floatx4 a = acc[mi][ni];
        uint4 o;
        o.x = sortkey(2.f*a.x - xx4.x, rquad+0);
        o.y = sortkey(2.f*a.y - xx4.y, rquad+1);
        o.z = sortkey(2.f*a.z - xx4.z, rquad+2);
        o.w = sortkey(2.f*a.w - xx4.w, rquad+3);
        *(uint4*)(PD + ((size_t)b*NPTS + n)*NPTS + mbase) = o;
      }
  } else {
    // ---- lin path (body identical to measured lin_gemm64) ----
    float* As = (float*)smem;        // [16][68]
    float* Bs = As + 16*68;          // [16][68]
    int m0 = (blockIdx.y - 16) * 64;
    int n0 = blockIdx.x * 64;
    const float* Xb = X + (size_t)b*bstride + (size_t)coff*NPTS;
    float acc[4][4] = {};
    int lr = t >> 4, lc = (t & 15) << 2;
    int tr = (t >> 4) << 2, tc = (t & 15) << 2;
    for (int k0 = 0; k0 < Cdim; k0 += 16){
      int c = k0 + lr;
      float4 av = make_float4(0,0,0,0);
      if (c < Cdim){
        #pragma unroll
        for (int j = 0; j < 4; ++j){
          int m = m0 + lc + j;
          float aval = (m < O) ? W[(size_t)m*lda + c]
                               : W[(size_t)(m-O)*lda + Cdim + c] - W[(size_t)(m-O)*lda + c];
          ((float*)&av)[j] = aval;
        }
      }
      float4 bv = make_float4(0,0,0,0);
      if (c < Cdim)
        bv = *(const float4*)(Xb + (size_t)c*NPTS + n0 + lc);
      *(float4*)&As[lr*68 + lc] = av;
      *(float4*)&Bs[lr*68 + lc] = bv;
      __syncthreads();
      #pragma unroll
      for (int kk = 0; kk < 16; ++kk){
        float4 a4 = *(const float4*)&As[kk*68 + tr];
        float4 b4 = *(const float4*)&Bs[kk*68 + tc];
        float a[4] = {a4.x,a4.y,a4.z,a4.w};
        float bb[4] = {b4.x,b4.y,b4.z,b4.w};
        #pragma unroll
        for (int i = 0; i < 4; ++i)
          #pragma unroll
          for (int j = 0; j < 4; ++j) acc[i][j] += a[i]*bb[j];
      }
      __syncthreads();
    }
    #pragma unroll
    for (int i = 0; i < 4; ++i){
      int m = m0 + tr + i;
      *(float4*)(V + ((size_t)b*M + m)*NPTS + n0 + tc) =
          make_float4(acc[i][0],acc[i][1],acc[i][2],acc[i][3]);
    }
  }
}

// ---------------- fused top-24 + f64 refine (keys pre-built; rank via LDS broadcast) ----------------
__global__ __launch_bounds__(256) void topk_refine(const unsigned* __restrict__ PD,
                                                   const float* __restrict__ X, long bstride,
                                                   int coff, int C,
                                                   const float* __restrict__ XT,
                                                   int* __restrict__ IDX){
  __shared__ double sp[4][32];
  __shared__ int    si[4][32];
  int wid = threadIdx.x >> 6;
  int lane = threadIdx.x & 63;
  int row = blockIdx.x*4 + wid;       // b*NPTS + n
  int b = row >> 10, n = row & 1023;
  const unsigned* p = PD + (size_t)row*NPTS;
  unsigned key[16];
  #pragma unroll
  for (int j4 = 0; j4 < 4; ++j4){
    uint4 t4 = *(const uint4*)&p[lane*16 + j4*4];
    key[j4*4+0] = t4.x; key[j4*4+1] = t4.y; key[j4*4+2] = t4.z; key[j4*4+3] = t4.w;
  }
  // bitonic sort 16 keys descending
  #pragma unroll
  for (int ksz = 2; ksz <= 16; ksz <<= 1){
    #pragma unroll
    for (int jj = ksz >> 1; jj > 0; jj >>= 1){
      #pragma unroll
      for (int i = 0; i < 16; ++i){
        int l = i ^ jj;
        if (l > i){
          unsigned a = key[i], c = key[l];
          unsigned mx = a > c ? a : c, mn = a > c ? c : a;
          bool maxfirst = ((i & ksz) == 0);
          key[i] = maxfirst ? mx : mn;
          key[l] = maxfirst ? mn : mx;
        }
      }
    }
  }
  int my_m = 0;
  #pragma unroll
  for (int k = 0; k < KC; ++k){
    unsigned h = key[0];
    unsigned g = h, o;
    o = (unsigned)__builtin_amdgcn_update_dpp(0, (int)g, 0x121, 0xF, 0xF, true);
    g = o > g ? o : g;
    o = (unsigned)__builtin_amdgcn_update_dpp(0, (int)g, 0x122, 0xF, 0xF, true);
    g = o > g ? o : g;
    o = (unsigned)__builtin_amdgcn_update_dpp(0, (int)g, 0x124, 0xF, 0xF, true);
    g = o > g ? o : g;
    o = (unsigned)__builtin_amdgcn_update_dpp(0, (int)g, 0x128, 0xF, 0xF, true);
    g = o > g ? o : g;
    o = (unsigned)__builtin_amdgcn_ds_swizzle((int)g, 0x401F);
    g = o > g ? o : g;
    o = (unsigned)__shfl_xor((int)g, 32, 64);
    g = o > g ? o : g;
    unsigned long long ball = __ballot(h == g);
    int wl = __ffsll(ball) - 1;
    if ((lane & 31) == k) my_m = wl*16 + (int)(g & 15u);   // lanes k AND k+32 record
    bool isw = (lane == wl);
    #pragma unroll
    for (int i2 = 0; i2 < 15; ++i2) key[i2] = isw ? key[i2+1] : key[i2];
    key[15] = isw ? 0u : key[15];
  }
  // exact f64 refine, split: lane k sums c in [0,C/2), lane k+32 sums [C/2,C)
  int lk = lane & 31;
  double pdv = -1e300; int midx = (1 << 20) + lane;
  if (lk < KC){
    midx = my_m;
    double dot = 0.0, m2 = 0.0, n2 = 0.0;
    if (C == 3){
      if (lane < 32){
        const float* Xb = X + (size_t)b*bstride + (size_t)coff*NPTS;
        #pragma unroll
        for (int c = 0; c < 3; ++c){
          double xn = (double)Xb[(size_t)c*NPTS + n];
          double xm = (double)Xb[(size_t)c*NPTS + my_m];
          dot += xn*xm; m2 += xm*xm; n2 += xn*xn;
        }
      }
    } else {
      int C2 = C >> 1;
      int cbeg = (lane < 32) ? 0 : C2;
      int cend = (lane < 32) ? C2 : C;
      const float* rn = XT + ((size_t)b*NPTS + n)*C;
      const float* rm = XT + ((size_t)b*NPTS + my_m)*C;
      for (int c = cbeg; c < cend; c += 4){
        float4 xn4 = *(const float4*)&rn[c];
        float4 xm4 = *(const float4*)&rm[c];
        dot += (double)xn4.x*(double)xm4.x + (double)xn4.y*(double)xm4.y
             + (double)xn4.z*(double)xm4.z + (double)xn4.w*(double)xm4.w;
        m2  += (double)xm4.x*(double)xm4.x + (double)xm4.y*(double)xm4.y
             + (double)xm4.z*(double)xm4.z + (double)xm4.w*(double)xm4.w;
        n2  += (double)xn4.x*(double)xn4.x + (double)xn4.y*(double)xn4.y
             + (double)xn4.z*(double)xn4.z + (double)xn4.w*(double)xn4.w;
      }
    }
    double od = __shfl_xor(dot, 32, 64);
    double om = __shfl_xor(m2, 32, 64);
    double on = __shfl_xor(n2, 32, 64);
    dot += od; m2 += om; n2 += on;
    pdv = (2.0*dot - m2) - n2;
  }
  // rank via same-wave LDS broadcast
  if (lane < KC){ sp[wid][lane] = pdv; si[wid][lane] = midx; }
  int rank = 0;
  #pragma unroll
  for (int j = 0; j < KC; ++j){
    double ov = sp[wid][j];
    int    oi = si[wid][j];
    rank += (ov > pdv || (ov == pdv && oi < midx)) ? 1 : 0;
  }
  if (lane < KC && rank < KNN) IDX[(size_t)row*KNN + rank] = midx;
}

// ---------------- per (b,o): ymax/ymin over k of (u[n] + v[idx[n,k]]) + BN partial sums --------
__global__ void edge_stats(const float* __restrict__ V, const int* __restrict__ IDX, int O,
                           float* __restrict__ YMX, float* __restrict__ YMN,
                           float* __restrict__ S1P, float* __restrict__ S2P){
  __shared__ float vrow[NPTS];
  __shared__ float urow[NPTS];
  __shared__ float r1[256];
  __shared__ float r2[256];
  int b = blockIdx.x / O;
  int o = blockIdx.x % O;
  int t = threadIdx.x;
  const float* vp = V + ((size_t)b*2*O + o)*NPTS;
  const float* up = V + ((size_t)b*2*O + O + o)*NPTS;
  for (int i = 0; i < 4; ++i){ vrow[t+256*i] = vp[t+256*i]; urow[t+256*i] = up[t+256*i]; }
  __syncthreads();
  float s1 = 0.f, s2 = 0.f;
  size_t obase = ((size_t)b*O + o)*NPTS;
  for (int i = 0; i < 4; ++i){
    int n = t + 256*i;
    float un = urow[n];
    const int* ip = IDX + ((size_t)b*NPTS + n)*KNN;
    float mx = -1e38f, mn = 1e38f;
    #pragma unroll
    for (int k = 0; k < KNN; ++k){
      float val = un + vrow[ip[k]];
      mx = fmaxf(mx, val); mn = fminf(mn, val);
      s1 += val; s2 += val*val;
    }
    YMX[obase + n] = mx;
    YMN[obase + n] = mn;
  }
  r1[t] = s1; r2[t] = s2;
  __syncthreads();
  for (int s = 128; s > 0; s >>= 1){
    if (t < s){ r1[t] += r1[t+s]; r2[t] += r2[t+s]; }
    __syncthreads();
  }
  if (t == 0){ S1P[b*O + o] = r1[0]; S2P[b*O + o] = r2[0]; }
}

// ---------------- apply BN(inline finalize)+lrelu to max-over-k, write into CAT slice ----------------
__global__ void edge_apply(const float* __restrict__ YMX, const float* __restrict__ YMN,
                           const float* __restrict__ S1P, const float* __restrict__ S2P,
                           const float* __restrict__ gw, const float* __restrict__ gb,
                           int O, float* __restrict__ CAT, int coff_out){
  int g = blockIdx.x*blockDim.x + threadIdx.x;
  int n = g & (NPTS-1);
  int o = (g >> 10) % O;
  int b = (g >> 10) / O;
  float s1 = 0.f, s2 = 0.f;
  #pragma unroll
  for (int i = 0; i < NBATCH; ++i){ s1 += S1P[i*O + o]; s2 += S2P[i*O + o]; }
  const float cnt = (float)(NBATCH*NPTS*KNN);
  float mean = s1 / cnt;
  float var = fmaxf(s2 / cnt - mean*mean, 0.f);
  float sc = gw[o] * rsqrtf(var + EPSBN);
  float sh = gb[o] - mean*sc;
  float v = (sc >= 0.f) ? YMX[g] : YMN[g];
  CAT[((size_t)b*512 + coff_out + o)*NPTS + n] = lrelu_f(sc*v + sh);
}

// ---------------- FUSED conv5 prep: catsplit_t (z<NBATCH) + wsplit (z==NBATCH) ----------------
__global__ void conv5_prep(const float* __restrict__ CAT,
                           unsigned short* __restrict__ Th, unsigned short* __restrict__ Tl,
                           const float* __restrict__ W,
                           unsigned short* __restrict__ Wh, unsigned short* __restrict__ Wl){
  __shared__ float tile[32][33];
  int t = threadIdx.x;
  if (blockIdx.z < NBATCH){
    int b = blockIdx.z;
    int c0 = blockIdx.y * 32;
    int n0 = blockIdx.x * 32;
    int r = t >> 3, q = t & 7;
    float4 rv = *(const float4*)(CAT + ((size_t)b*512 + c0 + r)*NPTS + n0 + q*4);
    tile[r][q*4+0] = rv.x; tile[r][q*4+1] = rv.y; tile[r][q*4+2] = rv.z; tile[r][q*4+3] = rv.w;
    __syncthreads();
    ushort4 oh, ol;
    float f0 = tile[q*4+0][r], f1 = tile[q*4+1][r], f2 = tile[q*4+2][r], f3 = tile[q*4+3][r];
    oh.x = f2bf_rne(f0); ol.x = f2bf_rne(f0 - bf2f(oh.x));
    oh.y = f2bf_rne(f1); ol.y = f2bf_rne(f1 - bf2f(oh.y));
    oh.z = f2bf_rne(f2); ol.z = f2bf_rne(f2 - bf2f(oh.z));
    oh.w = f2bf_rne(f3); ol.w = f2bf_rne(f3 - bf2f(oh.w));
    size_t ob = ((size_t)b*NPTS + n0 + r)*512 + c0 + q*4;
    *(ushort4*)(Th + ob) = oh;
    *(ushort4*)(Tl + ob) = ol;
  } else {
    int bid = blockIdx.x + 32*blockIdx.y;          // 0..511
    for (int i = bid*256 + t; i < 1024*512; i += 512*256){
      float f = W[i];
      unsigned short hi = f2bf_rne(f);
      Wh[i] = hi;
      Wl[i] = f2bf_rne(f - bf2f(hi));
    }
  }
}

// ---------------- conv5 via bf16x3 MFMA, 128n x 64m tile (1024 blocks, 4/CU) ----------------
__global__ __launch_bounds__(256) void conv5_mfma(
    const unsigned short* __restrict__ Ath, const unsigned short* __restrict__ Atl,
    const unsigned short* __restrict__ Wh,  const unsigned short* __restrict__ Wl,
    float* __restrict__ OUT){
  __shared__ __align__(16) unsigned short Ah[128*LROW];
  __shared__ __align__(16) unsigned short Al[128*LROW];
  __shared__ __align__(16) unsigned short Bh[64*LROW];
  __shared__ __align__(16) unsigned short Bl[64*LROW];
  int b  = blockIdx.z;
  int n0 = blockIdx.x * 128;
  int m0 = blockIdx.y * 64;
  int t = threadIdx.x;
  int lane = t & 63, wid = t >> 6;
  int wn = (wid & 1) * 64;
  int wm = (wid >> 1) * 32;
  int fr = lane & 15;
  int fq = (lane >> 4) * 8;
  floatx4 acc[4][2];
  #pragma unroll
  for (int i = 0; i < 4; ++i)
    #pragma unroll
    for (int j = 0; j < 2; ++j) acc[i][j] = (floatx4)(0.f);

  int srowB = t >> 2, spartB = (t & 3)*8;
  for (int k0 = 0; k0 < 512; k0 += 32){
    #pragma unroll
    for (int c = 0; c < 2; ++c){
      int ch = t + 256*c;
      int row = ch >> 2, part = (ch & 3)*8;
      size_t ga = ((size_t)b*NPTS + n0 + row)*512 + k0 + part;
      *(short8_t*)&Ah[row*LROW + part] = *(const short8_t*)&Ath[ga];
      *(short8_t*)&Al[row*LROW + part] = *(const short8_t*)&Atl[ga];
    }
    {
      size_t gb = ((size_t)(m0 + srowB))*512 + k0 + spartB;
      *(short8_t*)&Bh[srowB*LROW + spartB] = *(const short8_t*)&Wh[gb];
      *(short8_t*)&Bl[srowB*LROW + spartB] = *(const short8_t*)&Wl[gb];
    }
    __syncthreads();
    short8_t afh[4], afl[4], bfh[2], bfl[2];
    #pragma unroll
    for (int ni = 0; ni < 4; ++ni){
      int r = (wn + ni*16 + fr)*LROW + fq;
      afh[ni] = *(const short8_t*)&Ah[r];
      afl[ni] = *(const short8_t*)&Al[r];
    }
    #pragma unroll
    for (int mi = 0; mi < 2; ++mi){
      int r = (wm + mi*16 + fr)*LROW + fq;
      bfh[mi] = *(const short8_t*)&Bh[r];
      bfl[mi] = *(const short8_t*)&Bl[r];
    }
    #pragma unroll
    for (int ni = 0; ni < 4; ++ni)
      #pragma unroll
      for (int mi = 0; mi < 2; ++mi){
        acc[ni][mi] = __builtin_amdgcn_mfma_f32_16x16x32_bf16(afh[ni], bfh[mi], acc[ni][mi], 0, 0, 0);
        acc[ni][mi] = __builtin_amdgcn_mfma_f32_16x16x32_bf16(afl[ni], bfh[mi], acc[ni][mi], 0, 0, 0);
        acc[ni][mi] = __builtin_amdgcn_mfma_f32_16x16x32_bf16(afh[ni], bfl[mi], acc[ni][mi], 0, 0, 0);
      }
    __syncthreads();
  }
  int col = lane & 15;
  int rquad = (lane >> 4) * 4;
  #pragma unroll
  for (int ni = 0; ni < 4; ++ni)
    #pragma unroll
    for (int mi = 0; mi < 2; ++mi){
      int m = m0 + wm + mi*16 + col;
      int n = n0 + wn + ni*16 + rquad;
      *(floatx4*)(OUT + ((size_t)b*1024 + m)*NPTS + n) = acc[ni][mi];
    }
}

// ---------------- conv5 BN stats ----------------
__global__ void y5_stats(const float* __restrict__ Y5, float* __restrict__ S1, float* __restrict__ S2){
  __shared__ float r1[256], r2[256];
  int o = blockIdx.x;
  int t = threadIdx.x;
  float s1 = 0.f, s2 = 0.f;
  for (int b = 0; b < NBATCH; ++b){
    const float* p = Y5 + ((size_t)b*1024 + o)*NPTS;
    for (int n = t; n < NPTS; n += 256){ float v = p[n]; s1 += v; s2 += v*v; }
  }
  r1[t] = s1; r2[t] = s2;
  __syncthreads();
  for (int s = 128; s > 0; s >>= 1){
    if (t < s){ r1[t] += r1[t+s]; r2[t] += r2[t+s]; }
    __syncthreads();
  }
  if (t == 0){ S1[o] = r1[0]; S2[o] = r2[0]; }
}

// ---------------- head: feat = [max_n, mean_n] of lrelu(BN(y5)), inline finalize ----------------
__global__ void head_kernel(const float* __restrict__ Y5, const float* __restrict__ S1,
                            const float* __restrict__ S2,
                            const float* __restrict__ gw, const float* __restrict__ gb,
                            float* __restrict__ FEAT){
  __shared__ float rm[256], rs[256];
  int o = blockIdx.x & 1023;
  int b = blockIdx.x >> 10;
  int t = threadIdx.x;
  const float cnt = (float)(NBATCH*NPTS);
  float mean = S1[o] / cnt;
  float var = fmaxf(S2[o] / cnt - mean*mean, 0.f);
  float s = gw[o] * rsqrtf(var + EPSBN);
  float sh = gb[o] - mean*s;
  const float* p = Y5 + ((size_t)b*1024 + o)*NPTS;
  float mx = -1e38f, sm = 0.f;
  for (int n = t; n < NPTS; n += 256){
    float v = lrelu_f(s*p[n] + sh);
    mx = fmaxf(mx, v); sm += v;
  }
  rm[t] = mx; rs[t] = sm;
  __syncthreads();
  for (int st = 128; st > 0; st >>= 1){
    if (t < st){ rm[t] = fmaxf(rm[t], rm[t+st]); rs[t] += rs[t+st]; }
    __syncthreads();
  }
  if (t == 0){
    FEAT[(size_t)b*2048 + o]        = rm[0];
    FEAT[(size_t)b*2048 + 1024 + o] = rs[0] * (1.f/NPTS);
  }
}

// ---------------- FC + batch-BN(8) + lrelu ----------------
__global__ void fc_bn(const float* __restrict__ IN, int ID, int OD,
                      const float* __restrict__ W, const float* __restrict__ bias,
                      const float* __restrict__ gw, const float* __restrict__ gb,
                      float* __restrict__ OUT){
  __shared__ float red[256][8];
  int f = blockIdx.x;
  int t = threadIdx.x;
  float acc[8] = {};
  const float* wr = W + (size_t)f*ID;
  for (int j = t; j < ID; j += 256){
    float wv = wr[j];
    #pragma unroll
    for (int b = 0; b < 8; ++b) acc[b] += IN[b*ID + j] * wv;
  }
  #pragma unroll
  for (int b = 0; b < 8; ++b) red[t][b] = acc[b];
  __syncthreads();
  for (int s = 128; s > 0; s >>= 1){
    if (t < s){
      #pragma unroll
      for (int b = 0; b < 8; ++b) red[t][b] += red[t+s][b];
    }
    __syncthreads();
  }
  if (t == 0){
    float h[8], mean = 0.f;
    #pragma unroll
    for (int b = 0; b < 8; ++b){ h[b] = red[0][b] + bias[f]; mean += h[b]; }
    mean *= 0.125f;
    float var = 0.f;
    #pragma unroll
    for (int b = 0; b < 8; ++b){ float d = h[b]-mean; var += d*d; }
    var *= 0.125f;
    float sc = gw[f]*rsqrtf(var + EPSBN);
    float sh = gb[f] - mean*sc;
    #pragma unroll
    for (int b = 0; b < 8; ++b) OUT[b*OD + f] = lrelu_f(sc*h[b] + sh);
  }
}

// ---------------- final linear (no BN) ----------------
__global__ void fc_out(const float* __restrict__ IN, const float* __restrict__ W,
                       const float* __restrict__ bias, float* __restrict__ OUT){
  __shared__ float red[256][8];
  int j = blockIdx.x;
  int t = threadIdx.x;
  float wv = W[(size_t)j*256 + t];
  #pragma unroll
  for (int b = 0; b < 8; ++b) red[t][b] = IN[b*256 + t] * wv;
  __syncthreads();
  for (int s = 128; s > 0; s >>= 1){
    if (t < s){
      #pragma unroll
      for (int b = 0; b < 8; ++b) red[t][b] += red[t+s][b];
    }
    __syncthreads();
  }
  if (t == 0){
    #pragma unroll
    for (int b = 0; b < 8; ++b) OUT[b*40 + j] = red[0][b] + bias[j];
  }
}

extern "C" void kernel_launch(void* const* d_in, const int* in_sizes, int n_in,
                              void* d_out, int out_size, void* d_ws, size_t ws_size,
                              hipStream_t stream) {
  const float* x   = (const float*)d_in[0];
  const float* cw[5] = { (const float*)d_in[1], (const float*)d_in[2], (const float*)d_in[3],
                         (const float*)d_in[4], (const float*)d_in[5] };
  const float* bw[7]; const float* bbv[7];
  for (int i = 0; i < 7; ++i){ bw[i] = (const float*)d_in[6+2*i]; bbv[i] = (const float*)d_in[7+2*i]; }
  const float* l1w = (const float*)d_in[20]; const float* l1b = (const float*)d_in[21];
  const float* l2w = (const float*)d_in[22]; const float* l2b = (const float*)d_in[23];
  const float* l3w = (const float*)d_in[24]; const float* l3b = (const float*)d_in[25];
  float* out = (float*)d_out;

  float* ws = (float*)d_ws;
  unsigned* PD = (unsigned*)ws;            // u32 sortable keys (edge phase)
  float* V     = ws;
  float* YMX   = ws + 4194304;
  float* YMN   = ws + 6291456;
  float* Y5    = ws;
  float* XT    = ws + 8388608;
  unsigned short* XSH = (unsigned short*)(ws + 9437184);
  unsigned short* XSL = (unsigned short*)(ws + 9961472);
  float* XX    = ws + 10485760;
  unsigned short* CATth = (unsigned short*)(ws + 8388608);
  unsigned short* CATtl = (unsigned short*)(ws + 10485760);
  unsigned short* WhP   = (unsigned short*)(ws + 12582912);
  unsigned short* WlP   = (unsigned short*)(ws + 12845056);
  float* CAT   = ws + 16777216;
  int*   IDX   = (int*)(ws + 20987904);
  float* S1P   = ws + 21151744;
  float* S2P   = ws + 21159936;
  float* FEAT  = ws + 21170176;
  float* H1    = ws + 21186560;
  float* H2    = ws + 21190656;

  struct L { int C, Cp, O; const float* in; long bs; int ci; const float* w; int bn; int co; };
  L ls[4] = {
    { 3,   32,  64, x,   (long)3*NPTS,   0,   cw[0], 0, 0   },
    { 64,  64,  64, CAT, (long)512*NPTS, 0,   cw[1], 1, 64  },
    { 64,  64, 128, CAT, (long)512*NPTS, 64,  cw[2], 2, 128 },
    { 128, 128,256, CAT, (long)512*NPTS, 128, cw[3], 3, 256 },
  };

  // NOTE: pd writes PD (aliases V region? NO — PD aliases V both at ws+0!).
  // pd_lin runs pd (writes PD=ws) and lin (writes V=ws) CONCURRENTLY — they must not alias.
  // Move V to a disjoint region: V needs 2*O*NPTS*NBATCH <= 4M floats. Place V at ws+10M+16K.. no:
  // use region [ws+12582912+1M...]: WhP/WlP are conv5-phase only. V at ws+11534336 (11M..15M is
  // inside XX/CATtl conv5 area but edge-phase free EXCEPT XX at 10485760 (8K floats).
  // Safe edge-phase free span: [ws+10493952, ws+16777216) = 6.0M floats > 4M needed.
  float* Vd = ws + 10493952;   // disjoint from PD (0..8M), XT, XSH/XSL, XX

  for (int li = 0; li < 4; ++li){
    L& l = ls[li];
    prep<<<dim3(32, NBATCH), 256, 0, stream>>>(l.in, l.bs, l.ci, l.C, l.Cp, XSH, XSL, XT, XX);
    pd_lin<<<dim3(16, 16 + (2*l.O)/64, NBATCH), 256, 0, stream>>>(
        XSH, XSL, l.Cp, XX, PD,
        l.w, 2*l.O, l.C, 2*l.C, l.O, l.in, l.bs, l.ci, Vd);
    topk_refine<<<(NBATCH*NPTS)/4, 256, 0, stream>>>(PD, l.in, l.bs, l.ci, l.C, XT, IDX);
    edge_stats<<<NBATCH*l.O, 256, 0, stream>>>(Vd, IDX, l.O, YMX, YMN, S1P, S2P);
    edge_apply<<<(NBATCH*l.O*NPTS)/256, 256, 0, stream>>>(
        YMX, YMN, S1P, S2P, bw[l.bn], bbv[l.bn], l.O, CAT, l.co);
  }

  // conv5: fused prep (catsplit + wsplit), then MFMA (128n x 64m tiles)
  conv5_prep<<<dim3(32,16,NBATCH+1), 256, 0, stream>>>(CAT, CATth, CATtl, cw[4], WhP, WlP);
  conv5_mfma<<<dim3(8,16,NBATCH), 256, 0, stream>>>(CATth, CATtl, WhP, WlP, Y5);

  y5_stats<<<1024, 256, 0, stream>>>(Y5, S1P, S2P);
  head_kernel<<<NBATCH*1024, 256, 0, stream>>>(Y5, S1P, S2P, bw[4], bbv[4], FEAT);

  fc_bn<<<512, 256, 0, stream>>>(FEAT, 2048, 512, l1w, l1b, bw[5], bbv[5], H1);
  fc_bn<<<256, 256, 0, stream>>>(H1, 512, 256, l2w, l2b, bw[6], bbv[6], H2);
  fc_out<<<40, 256, 0, stream>>>(H2, l3w, l3b, out);
}